// Round 9
// baseline (167.343 us; speedup 1.0000x reference)
//
#include <hip/hip_runtime.h>
#include <math.h>

// Problem constants
// B=2, H=128, W=256, MD=34, LD=32, NH=4, HD=8, SH=64, K=25, P=7, R=3,
// FF1=512, FF2=256

typedef __attribute__((ext_vector_type(8))) short bfrag;    // 8 bf16 = 4 VGPR
typedef __attribute__((ext_vector_type(4))) float ffrag;    // 4 f32 acc
typedef __attribute__((ext_vector_type(4))) short short4v;  // 8B

union bfi4 { int4 i; bfrag b; };

// Fast tanh-form GELU (~7 VALU ops, |err| vs erf-GELU ~3e-3)
__device__ __forceinline__ float gelu_f(float v) {
  const float z = v * (2.3022077484f + 0.1029451564f * v * v);  // log2e folded
  const float e = __builtin_amdgcn_exp2f(-z);
  return v * __builtin_amdgcn_rcpf(1.0f + e);
}

// exact RNE (cold paths: weight prep)
__device__ __forceinline__ short f2bf(float f) {
  union { float f; unsigned u; } v; v.f = f;
  unsigned r = (v.u + 0x7fffu + ((v.u >> 16) & 1u)) >> 16;
  return (short)r;
}

// round-half-up (2 VALU ops)
__device__ __forceinline__ short f2bf_fast(float f) {
  union { float f; unsigned u; } v; v.f = f;
  return (short)((v.u + 0x8000u) >> 16);
}

__device__ __forceinline__ float bf2f(short s) {
  union { float f; unsigned u; } v;
  v.u = ((unsigned)(unsigned short)s) << 16;
  return v.f;
}

// pack two f32 -> bf16 pair in one dword: (bf(b)<<16)|bf(a); 3 VALU ops
__device__ __forceinline__ int pkbf(float a, float b) {
  union { float f; unsigned u; } va, vb; va.f = a; vb.f = b;
  return (int)__builtin_amdgcn_perm(vb.u + 0x8000u, va.u + 0x8000u, 0x07060302u);
}

// staged bf16 short4 store helper
__device__ __forceinline__ void st4bf(short* p, float4 v) {
  short4v s;
  s[0] = f2bf(v.x); s[1] = f2bf(v.y); s[2] = f2bf(v.z); s[3] = f2bf(v.w);
  *(short4v*)p = s;
}

// XCD-aware bijective remap (8 XCDs x 256 slots; 16 slots share one h)
__device__ __forceinline__ void tile_map(int& w0, int& b, int& h, int& lin) {
  lin  = blockIdx.x + (blockIdx.y << 3) + (blockIdx.z << 10);
  const int xcd  = lin & 7;
  const int slot = lin >> 3;
  w0 = (slot & 7) * 32;
  b  = (slot >> 3) & 1;
  h  = (xcd << 4) | (slot >> 4);
}

// ---------------------------------------------------------------------------
// K01: weight prep (unchanged from round 8).
// bid 0..511: fused conv+MLP1 fragments per (h, n); head-MLP bias baked into
// dead K-slot 56. bid 512..527: fw2 kt transposes. 528..529: fw1 halves.
// 530: fw3.
// ---------------------------------------------------------------------------
__global__ __launch_bounds__(256) void k01_prep(
    const float* __restrict__ psi, const float* __restrict__ dw,
    const float* __restrict__ db,
    const float* __restrict__ fw1, const float* __restrict__ fw2,
    const float* __restrict__ fw3, const float* __restrict__ hw1,
    const float* __restrict__ hb1,
    short* __restrict__ wcb, short* __restrict__ fw1s,
    short* __restrict__ fw2s, short* __restrict__ fw3s) {
  __shared__ __align__(16) char sm[24960];
  const int bid = blockIdx.x;
  const int tid = threadIdx.x;

  if (bid < 512) {            // ---- fused conv+MLP1 fragments per (h, n)
    float* tileL  = (float*)sm;               // [64][52] f32   = 13312 B
    float* hw1n   = (float*)(sm + 13312);     // [64][32] f32   =  8192 B
    short* tile2  = (short*)(sm + 21504);     // [32][52] bf16  =  3328 B
    float* bias32 = (float*)(sm + 24832);     // [32] f32       =   128 B
    const int h = bid >> 2;
    const int n = bid & 3;
    const int lane = tid & 63;
    const int w = __builtin_amdgcn_readfirstlane(tid >> 6);

    for (int e = tid; e < 512; e += 256)
      ((float4*)hw1n)[e] = ((const float4*)(hw1 + n * 2048))[e];

    float dwreg[25];
#pragma unroll
    for (int kk = 0; kk < 25; ++kk) dwreg[kk] = dw[lane * 25 + kk];
    const int p0 = w * 13;
    const int pend = (p0 + 13 < 49) ? (p0 + 13) : 49;
#pragma unroll 1
    for (int p = p0; p < pend; ++p) {
      float ae = 0.f, ao = 0.f;           // 2 chains
#pragma unroll
      for (int kk = 0; kk < 24; kk += 2) {
        ae += dwreg[kk]     * psi[kk * 6272 + h * 49 + p];
        ao += dwreg[kk + 1] * psi[(kk + 1) * 6272 + h * 49 + p];
      }
      ae += dwreg[24] * psi[24 * 6272 + h * 49 + p];
      tileL[lane * 52 + p] = ae + ao;
    }
    __syncthreads();

    // head-MLP bias (exact f32): bias32[o] = hb1[n][o] + sum_s hw1n[s][o]*db[s]
    if (tid >= 224) {
      const int o = tid - 224;
      float acc = hb1[n * 32 + o];
#pragma unroll 4
      for (int s = 0; s < 64; ++s) acc += hw1n[s * 32 + o] * db[s];
      bias32[o] = acc;
    }

    const int o = tid & 31;
#pragma unroll 1
    for (int pp = tid >> 5; pp < 25; pp += 8) {
      const int p2 = pp * 2;
      float a0 = 0.f, a1 = 0.f, a2 = 0.f, a3 = 0.f;   // 4 chains
#pragma unroll 4
      for (int f = 0; f < 64; f += 2) {
        const float wv0 = hw1n[f * 32 + o];
        const float wv1 = hw1n[(f + 1) * 32 + o];
        a0 += wv0 * tileL[f * 52 + p2];
        a1 += wv0 * tileL[f * 52 + p2 + 1];
        a2 += wv1 * tileL[(f + 1) * 52 + p2];
        a3 += wv1 * tileL[(f + 1) * 52 + p2 + 1];
      }
      tile2[o * 52 + p2] = f2bf(a0 + a2);
      if (p2 + 1 < 49) tile2[o * 52 + p2 + 1] = f2bf(a1 + a3);
    }
    __syncthreads();

    short* outp = wcb + h * 16384 + n * 4096;
    for (int idx = tid; idx < 4096; idx += 256) {
      const int jj = idx & 7, ln = (idx >> 3) & 63;
      const int nt = (idx >> 9) & 1, kt = (idx >> 10) & 1;
      const int par = idx >> 11;
      const int k = kt * 32 + ((ln >> 4) << 3) + jj;
      const int oo = nt * 16 + (ln & 15);
      const int r = k >> 3, dlt = k & 7;
      const int j = par ? (dlt - 1) : dlt;
      short v = 0;
      if (r < 7 && j >= 0 && j < 7) v = tile2[oo * 52 + r * 7 + j];
      if (k == 56) v = f2bf(bias32[oo]);   // bias in dead K-slot
      outp[idx] = v;
    }
    return;
  }

  if (bid < 528) {            // ---- fw2 kt-tile transpose: K rows 32, N 256
    short* S = (short*)sm;               // [32][260]
    const int kt = bid - 512;
    const float* src = fw2 + kt * 8192;
    for (int q = tid; q < 2048; q += 256) {
      const int lin = q * 4;
      const int kk = lin >> 8, nn = lin & 255;
      st4bf(S + kk * 260 + nn, *(const float4*)(src + lin));
    }
    __syncthreads();
    short* dst = fw2s + kt * 8192;
    for (int q = tid; q < 8192; q += 256) {
      const int jj = q & 7, lane = (q >> 3) & 63, nt = q >> 9;
      const int kk = (lane >> 4) * 8 + jj, nn = nt * 16 + (lane & 15);
      dst[q] = S[kk * 260 + nn];
    }
    return;
  }

  if (bid < 530) {            // ---- fw1 transpose half X: K 32, N 256
    const int X = bid - 528;
    short* S = (short*)sm;               // [32][260]
    for (int q = tid; q < 2048; q += 256) {
      const int lin = q * 4;
      const int kk = lin >> 8, nn = lin & 255;
      st4bf(S + kk * 260 + nn, *(const float4*)(fw1 + kk * 512 + X * 256 + nn));
    }
    __syncthreads();
    for (int q = tid; q < 8192; q += 256) {
      const int jj = q & 7, lane = (q >> 3) & 63, ntl = q >> 9;
      const int kk = (lane >> 4) * 8 + jj, nn = ntl * 16 + (lane & 15);
      fw1s[X * 8192 + q] = S[kk * 260 + nn];
    }
    return;
  }

  {                           // ---- bid 530: fw3 transpose: K 256, N 32
    short* S = (short*)sm;               // [256][36]
    for (int q = tid; q < 2048; q += 256) {
      const int lin = q * 4;
      const int kk = lin >> 5, nn = lin & 31;
      st4bf(S + kk * 36 + nn, *(const float4*)(fw3 + lin));
    }
    __syncthreads();
    for (int q = tid; q < 8192; q += 256) {
      const int jj = q & 7, lane = (q >> 3) & 63;
      const int nt = (q >> 9) & 1, kt = q >> 10;
      const int kk = kt * 32 + (lane >> 4) * 8 + jj, nn = nt * 16 + (lane & 15);
      fw3s[q] = S[kk * 36 + nn];
    }
  }
}

// ---------------------------------------------------------------------------
// K23: DISCO conv (hw1-folded, bias-in-MFMA) + head-MLP tail + final MLP.
// grid (8,128,2), block 256, LDS 20384 B.
// R9 single-variable experiment: __launch_bounds__(256,7) = cap 72.
// R8's cap-64 spilled ~38 MB scratch (FETCH 24/WRITE 31 MB) because the
// kernel's natural peak is ~68-72 regs (phase-A: cw16+u16+h8+w0v/w1v8+addr;
// phase-B layer1: acc32 live + ~22 transient). R4 proved cap-7 runs this
// structure spill-free (FETCH 9.1/WRITE 8.7); since then the epilogue lost
// ~25% of its VALU work (operand swap + bias-in-MFMA), whose benefit was
// masked by spill. Cap-7 unmasks it: predicted ~63-68 us.
// LDS map: phase A sX [0,18080) + sM [18080,20384); phase B sT1h/sT2
// [0,16896) alias sX (sM survives), sO f32 [0,4352) behind a barrier.
// ---------------------------------------------------------------------------
__global__ __launch_bounds__(256, 7) void k23_fused(
    const float* __restrict__ x,    const short* __restrict__ wcb,
    const float* __restrict__ hw2,  const float* __restrict__ hb2,
    const short* __restrict__ fw1s, const short* __restrict__ fw2s,
    const short* __restrict__ fw3s,
    const float* __restrict__ fb1,  const float* __restrict__ fb2,
    const float* __restrict__ fb3,  float* __restrict__ outb) {
  __shared__ __align__(16) char smem[20384];
  short* sX = (short*)smem;                  // [32 ch][7 slots x 40] + guard
  short* sM = (short*)(smem + 18080);        // [32][36] bf16

  const int tid = threadIdx.x;
  int w0, b, h, lin;
  tile_map(w0, b, h, lin);

  const int lane = tid & 63, lm = lane & 15, lq = lane >> 4;
  const int n = tid >> 6;  // wave == head in phase A
  const int idx16 = (lane ^ 16) << 2;        // bpermute byte indices
  const int idx32 = (lane ^ 32) << 2;
  const unsigned injm = (lq == 3) ? 0xFFFFu : 0u;   // 1.0-tap inject mask

  const float hb2n = hb2[n];

  {  // zero-fill whole LDS (tap pads must be 0.0bf16, never garbage)
    int4* p = (int4*)smem;
    int4 z; z.x = z.y = z.z = z.w = 0;
    for (int e = tid; e < 20384 / 16; e += 256) p[e] = z;
  }
  __syncthreads();

  // stage x tile as bf16; channel stride 280 shorts; row r -> slot
  // {0,2,4,6,1,3,5} (slot stride 40 shorts) for conflict-free gathers
#pragma unroll 1
  for (int r = 0; r < 7; ++r) {
    int hr = h - 3 + r; hr = hr < 0 ? 0 : (hr > 127 ? 127 : hr);
    const int slot = (r < 4) ? (2 * r) : (2 * r - 7);
    const float* __restrict__ xrow = x + (size_t)((b * 128 + hr) * 256) * 34;
    short* __restrict__ sxr = sX + slot * 40;
    for (int e = tid; e < 39 * 16; e += 256) {
      const int c2 = e & 15;
      const int wp = e >> 4;
      const int wr = (w0 - 3 + wp) & 255;
      const float2 v = *(const float2*)&xrow[wr * 34 + c2 * 2];
      short* dp = sxr + (c2 * 2) * 280 + wp;
      dp[0]   = f2bf_fast(v.x);
      dp[280] = f2bf_fast(v.y);
    }
  }
  __syncthreads();

  const int* tpB = (const int*)sX;

  // per-lane hw2 scale for this lane's 8 o-rows (par-invariant, hoisted)
  const float4 w0v = *(const float4*)(hw2 + n * 32 + lq * 4);
  const float4 w1v = *(const float4*)(hw2 + n * 32 + 16 + lq * 4);

  // ---- phase A: A=weights(rows=o, bias in k=56), B=taps -> D[o, pixel]
#pragma unroll 1
  for (int par = 0; par < 2; ++par) {
    bfrag cw[2][2];
#pragma unroll
    for (int kt = 0; kt < 2; ++kt)
#pragma unroll
      for (int nt = 0; nt < 2; ++nt)
        cw[kt][nt] = *(const bfrag*)(wcb + h * 16384 + n * 4096 +
                         ((par * 2 + kt) * 2 + nt) * 512 + lane * 8);

#pragma unroll 1
    for (int i = 0; i < 8; ++i) {
      const int c = n * 8 + i;

      // tap B-frags: lane lm = pixel; u0 rows 0-3 (slots 2lq),
      // u1 rows 4-7 (slots 2lq+1)
      const int base0 = c * 140 + lq * 40 + lm;
      bfi4 u0, u1;
      u0.i.x = tpB[base0];      u0.i.y = tpB[base0 + 1];
      u0.i.z = tpB[base0 + 2];  u0.i.w = tpB[base0 + 3];
      u1.i.x = tpB[base0 + 20]; u1.i.y = tpB[base0 + 21];
      u1.i.z = tpB[base0 + 22]; u1.i.w = tpB[base0 + 23];
      // inject 1.0 at K-slot 56 (lq==3, entry jj=0 of u1) -> bias row fires
      u1.i.x = (int)(((unsigned)u1.i.x & ~injm) | (0x3F80u & injm));

      ffrag h0 = {0.f, 0.f, 0.f, 0.f}, h1 = {0.f, 0.f, 0.f, 0.f};
      h0 = __builtin_amdgcn_mfma_f32_16x16x32_bf16(cw[0][0], u0.b, h0, 0, 0, 0);
      h0 = __builtin_amdgcn_mfma_f32_16x16x32_bf16(cw[1][0], u1.b, h0, 0, 0, 0);
      h1 = __builtin_amdgcn_mfma_f32_16x16x32_bf16(cw[0][1], u0.b, h1, 0, 0, 0);
      h1 = __builtin_amdgcn_mfma_f32_16x16x32_bf16(cw[1][1], u1.b, h1, 0, 0, 0);

      // in-lane o-contraction (bias already in h), then 4-way lq reduce
      float s0 = gelu_f(h0[0]) * w0v.x;
      s0 += gelu_f(h0[1]) * w0v.y;
      s0 += gelu_f(h0[2]) * w0v.z;
      s0 += gelu_f(h0[3]) * w0v.w;
      float s1 = gelu_f(h1[0]) * w1v.x;
      s1 += gelu_f(h1[1]) * w1v.y;
      s1 += gelu_f(h1[2]) * w1v.z;
      s1 += gelu_f(h1[3]) * w1v.w;
      union { float f; int i; } sv, t1, t2;
      sv.f = s0 + s1;
      t1.i = __builtin_amdgcn_ds_bpermute(idx16, sv.i);
      sv.f += t1.f;
      t2.i = __builtin_amdgcn_ds_bpermute(idx32, sv.i);
      const float tot = sv.f + t2.f;

      const int p = 2 * lm + par;
      const float res = bf2f(sX[c * 280 + 243 + p]);  // center tap (slot 6)
      if (lq == 0) sM[p * 36 + c] = f2bf_fast(tot + hb2n + res);
    }
  }
  __syncthreads();

  // ---- phase B: fused MLP 32->512(gelu)->256(gelu)->32 (+residual)
  short* sT1h = (short*)smem;
  short* sT2  = (short*)smem;
  float* sO   = (float*)smem;
  const int wave = n;
  const int koff = lq * 8;
  const int mt3 = wave & 1;
  const int nt3 = wave >> 1;
  const int col3 = nt3 * 16 + lm;
  const int pixg = (b * 128 + h) * 256 + w0;
  const int n0 = wave * 4;

  ffrag acc[2][4];
#pragma unroll
  for (int mt = 0; mt < 2; ++mt)
#pragma unroll
    for (int ni = 0; ni < 4; ++ni) acc[mt][ni] = ffrag{0.f, 0.f, 0.f, 0.f};
  const short* w2base = fw2s + n0 * 512 + lane * 8;

#pragma unroll 1
  for (int H = 0; H < 2; ++H) {
    // layer 1, half H: A=fw1 frag (rows=ff1 cols), B=sM (cols=pixels)
#pragma unroll
    for (int ni = 0; ni < 4; ++ni) {
      const bfrag b1f = *(const bfrag*)(fw1s +
                          (H * 16 + wave * 4 + ni) * 512 + lane * 8);
      const int ntl = wave * 4 + ni;
      const float4 fb1v = *(const float4*)(fb1 + H * 256 + ntl * 16 + lq * 4);
#pragma unroll
      for (int mt = 0; mt < 2; ++mt) {
        const bfrag aFm = *(const bfrag*)(sM + (mt * 16 + lm) * 36 + koff);
        ffrag cc = {0.f, 0.f, 0.f, 0.f};
        cc = __builtin_amdgcn_mfma_f32_16x16x32_bf16(b1f, aFm, cc, 0, 0, 0);
        // D rows = 4 consecutive ff1 cols, col = pixel mt*16+lm -> b64 store
        int2 wv;
        wv.x = pkbf(gelu_f(cc[0] + fb1v.x), gelu_f(cc[1] + fb1v.y));
        wv.y = pkbf(gelu_f(cc[2] + fb1v.z), gelu_f(cc[3] + fb1v.w));
        *(int2*)(sT1h + (mt * 16 + lm) * 264 + ntl * 16 + lq * 4) = wv;
      }
    }
    __syncthreads();

    // layer 2: A=fw2 frag (rows=ff2 cols), B=sT1h (cols=pixels)
#pragma unroll 1
    for (int kt = 0; kt < 8; ++kt) {
      const bfrag a0 = *(const bfrag*)(sT1h + lm * 264 + kt * 32 + koff);
      const bfrag a1 = *(const bfrag*)(sT1h + (16 + lm) * 264 + kt * 32 + koff);
#pragma unroll
      for (int np = 0; np < 2; ++np) {
        const bfrag bv0 = *(const bfrag*)(w2base + (H * 8 + kt) * 8192 + (2 * np) * 512);
        const bfrag bv1 = *(const bfrag*)(w2base + (H * 8 + kt) * 8192 + (2 * np + 1) * 512);
        acc[0][2 * np]     = __builtin_amdgcn_mfma_f32_16x16x32_bf16(bv0, a0, acc[0][2 * np], 0, 0, 0);
        acc[1][2 * np]     = __builtin_amdgcn_mfma_f32_16x16x32_bf16(bv0, a1, acc[1][2 * np], 0, 0, 0);
        acc[0][2 * np + 1] = __builtin_amdgcn_mfma_f32_16x16x32_bf16(bv1, a0, acc[0][2 * np + 1], 0, 0, 0);
        acc[1][2 * np + 1] = __builtin_amdgcn_mfma_f32_16x16x32_bf16(bv1, a1, acc[1][2 * np + 1], 0, 0, 0);
      }
    }
    __syncthreads();   // before next half overwrites sT1h
  }

  // t2 epilogue: acc rows = 4 consecutive ff2 cols, col = pixel -> b64 store
#pragma unroll
  for (int mt = 0; mt < 2; ++mt)
#pragma unroll
    for (int ni = 0; ni < 4; ++ni) {
      const float4 fb2v = *(const float4*)(fb2 + (n0 + ni) * 16 + lq * 4);
      int2 wv;
      wv.x = pkbf(gelu_f(acc[mt][ni][0] + fb2v.x), gelu_f(acc[mt][ni][1] + fb2v.y));
      wv.y = pkbf(gelu_f(acc[mt][ni][2] + fb2v.z), gelu_f(acc[mt][ni][3] + fb2v.w));
      *(int2*)(sT2 + (mt * 16 + lm) * 264 + (n0 + ni) * 16 + lq * 4) = wv;
    }
  __syncthreads();

  // layer 3 (reads sT2; D rows = pixels as before)
  ffrag c3 = {0.f, 0.f, 0.f, 0.f};
  const short* sA3 = sT2 + (mt3 * 16 + lm) * 264 + koff;
#pragma unroll
  for (int kt = 0; kt < 8; ++kt) {
    const bfrag a = *(const bfrag*)(sA3 + kt * 32);
    const bfrag bw = *(const bfrag*)(fw3s + nt3 * 512 + kt * 1024 + lane * 8);
    c3 = __builtin_amdgcn_mfma_f32_16x16x32_bf16(a, bw, c3, 0, 0, 0);
  }
  __syncthreads();   // all sT2 reads done before sO overwrite
  {
    const float bias = fb3[col3];
#pragma unroll
    for (int r = 0; r < 4; ++r) {
      const int row = mt3 * 16 + lq * 4 + r;
      const float res = bf2f(sM[row * 36 + col3]);
      sO[row * 34 + col3] = c3[r] + bias + res;
    }
  }
  if (tid < 32) {   // sincos passthrough (x row L2-hot)
    const float2 scv =
        *(const float2*)&x[(size_t)(((b * 128 + h) * 256 + w0 + tid)) * 34 + 32];
    sO[tid * 34 + 32] = scv.x;
    sO[tid * 34 + 33] = scv.y;
  }
  __syncthreads();
  {
    const float4* sp = (const float4*)sO;           // 1088 floats = 272 f4
    float4* dp = (float4*)(outb + (size_t)pixg * 34);
    for (int e = tid; e < 272; e += 256) dp[e] = sp[e];
  }
}

// ---------------------------------------------------------------------------
extern "C" void kernel_launch(void* const* d_in, const int* in_sizes, int n_in,
                              void* d_out, int out_size, void* d_ws, size_t ws_size,
                              hipStream_t stream) {
  const float* x   = (const float*)d_in[0];
  const float* psi = (const float*)d_in[1];
  const float* dw  = (const float*)d_in[2];
  const float* db  = (const float*)d_in[3];
  const float* hw1 = (const float*)d_in[4];
  const float* hb1 = (const float*)d_in[5];
  const float* hw2 = (const float*)d_in[6];
  const float* hb2 = (const float*)d_in[7];
  const float* fw1 = (const float*)d_in[8];
  const float* fb1 = (const float*)d_in[9];
  const float* fw2 = (const float*)d_in[10];
  const float* fb2 = (const float*)d_in[11];
  const float* fw3 = (const float*)d_in[12];
  const float* fb3 = (const float*)d_in[13];
  float* outb = (float*)d_out;

  // workspace (~4.5 MB)
  short* wcb  = (short*)d_ws;        // 128*16384 = 2097152 shorts
  short* fw1s = wcb + 2097152;       // 16384
  short* fw2s = fw1s + 16384;        // 131072
  short* fw3s = fw2s + 131072;       // 8192

  hipLaunchKernelGGL(k01_prep, dim3(531), dim3(256), 0, stream,
                     psi, dw, db, fw1, fw2, fw3, hw1, hb1,
                     wcb, fw1s, fw2s, fw3s);
  hipLaunchKernelGGL(k23_fused, dim3(8, 128, 2), dim3(256), 0, stream,
                     x, wcb, hw2, hb2,
                     fw1s, fw2s, fw3s, fb1, fb2, fb3, outb);
}

// Round 10
// 166.716 us; speedup vs baseline: 1.0038x; 1.0038x over previous
//
#include <hip/hip_runtime.h>
#include <math.h>

// Problem constants
// B=2, H=128, W=256, MD=34, LD=32, NH=4, HD=8, SH=64, K=25, P=7, R=3,
// FF1=512, FF2=256

typedef __attribute__((ext_vector_type(8))) short bfrag;    // 8 bf16 = 4 VGPR
typedef __attribute__((ext_vector_type(4))) float ffrag;    // 4 f32 acc
typedef __attribute__((ext_vector_type(4))) short short4v;  // 8B

union bfi4 { int4 i; bfrag b; };

// Fast tanh-form GELU (~7 VALU ops, |err| vs erf-GELU ~3e-3)
__device__ __forceinline__ float gelu_f(float v) {
  const float z = v * (2.3022077484f + 0.1029451564f * v * v);  // log2e folded
  const float e = __builtin_amdgcn_exp2f(-z);
  return v * __builtin_amdgcn_rcpf(1.0f + e);
}

// exact RNE (cold paths: weight prep)
__device__ __forceinline__ short f2bf(float f) {
  union { float f; unsigned u; } v; v.f = f;
  unsigned r = (v.u + 0x7fffu + ((v.u >> 16) & 1u)) >> 16;
  return (short)r;
}

// round-half-up (2 VALU ops)
__device__ __forceinline__ short f2bf_fast(float f) {
  union { float f; unsigned u; } v; v.f = f;
  return (short)((v.u + 0x8000u) >> 16);
}

__device__ __forceinline__ float bf2f(short s) {
  union { float f; unsigned u; } v;
  v.u = ((unsigned)(unsigned short)s) << 16;
  return v.f;
}

// pack two f32 -> bf16 pair in one dword: (bf(b)<<16)|bf(a); 3 VALU ops
__device__ __forceinline__ int pkbf(float a, float b) {
  union { float f; unsigned u; } va, vb; va.f = a; vb.f = b;
  return (int)__builtin_amdgcn_perm(vb.u + 0x8000u, va.u + 0x8000u, 0x07060302u);
}

// staged bf16 short4 store helper
__device__ __forceinline__ void st4bf(short* p, float4 v) {
  short4v s;
  s[0] = f2bf(v.x); s[1] = f2bf(v.y); s[2] = f2bf(v.z); s[3] = f2bf(v.w);
  *(short4v*)p = s;
}

// XCD-aware bijective remap (8 XCDs x 256 slots; 16 slots share one h)
__device__ __forceinline__ void tile_map(int& w0, int& b, int& h, int& lin) {
  lin  = blockIdx.x + (blockIdx.y << 3) + (blockIdx.z << 10);
  const int xcd  = lin & 7;
  const int slot = lin >> 3;
  w0 = (slot & 7) * 32;
  b  = (slot >> 3) & 1;
  h  = (xcd << 4) | (slot >> 4);
}

// ---------------------------------------------------------------------------
// K01: weight prep (unchanged from round 8).
// bid 0..511: fused conv+MLP1 fragments per (h, n); head-MLP bias baked into
// dead K-slot 56. bid 512..527: fw2 kt transposes. 528..529: fw1 halves.
// 530: fw3.
// ---------------------------------------------------------------------------
__global__ __launch_bounds__(256) void k01_prep(
    const float* __restrict__ psi, const float* __restrict__ dw,
    const float* __restrict__ db,
    const float* __restrict__ fw1, const float* __restrict__ fw2,
    const float* __restrict__ fw3, const float* __restrict__ hw1,
    const float* __restrict__ hb1,
    short* __restrict__ wcb, short* __restrict__ fw1s,
    short* __restrict__ fw2s, short* __restrict__ fw3s) {
  __shared__ __align__(16) char sm[24960];
  const int bid = blockIdx.x;
  const int tid = threadIdx.x;

  if (bid < 512) {            // ---- fused conv+MLP1 fragments per (h, n)
    float* tileL  = (float*)sm;               // [64][52] f32   = 13312 B
    float* hw1n   = (float*)(sm + 13312);     // [64][32] f32   =  8192 B
    short* tile2  = (short*)(sm + 21504);     // [32][52] bf16  =  3328 B
    float* bias32 = (float*)(sm + 24832);     // [32] f32       =   128 B
    const int h = bid >> 2;
    const int n = bid & 3;
    const int lane = tid & 63;
    const int w = __builtin_amdgcn_readfirstlane(tid >> 6);

    for (int e = tid; e < 512; e += 256)
      ((float4*)hw1n)[e] = ((const float4*)(hw1 + n * 2048))[e];

    float dwreg[25];
#pragma unroll
    for (int kk = 0; kk < 25; ++kk) dwreg[kk] = dw[lane * 25 + kk];
    const int p0 = w * 13;
    const int pend = (p0 + 13 < 49) ? (p0 + 13) : 49;
#pragma unroll 1
    for (int p = p0; p < pend; ++p) {
      float ae = 0.f, ao = 0.f;           // 2 chains
#pragma unroll
      for (int kk = 0; kk < 24; kk += 2) {
        ae += dwreg[kk]     * psi[kk * 6272 + h * 49 + p];
        ao += dwreg[kk + 1] * psi[(kk + 1) * 6272 + h * 49 + p];
      }
      ae += dwreg[24] * psi[24 * 6272 + h * 49 + p];
      tileL[lane * 52 + p] = ae + ao;
    }
    __syncthreads();

    // head-MLP bias (exact f32): bias32[o] = hb1[n][o] + sum_s hw1n[s][o]*db[s]
    if (tid >= 224) {
      const int o = tid - 224;
      float acc = hb1[n * 32 + o];
#pragma unroll 4
      for (int s = 0; s < 64; ++s) acc += hw1n[s * 32 + o] * db[s];
      bias32[o] = acc;
    }

    const int o = tid & 31;
#pragma unroll 1
    for (int pp = tid >> 5; pp < 25; pp += 8) {
      const int p2 = pp * 2;
      float a0 = 0.f, a1 = 0.f, a2 = 0.f, a3 = 0.f;   // 4 chains
#pragma unroll 4
      for (int f = 0; f < 64; f += 2) {
        const float wv0 = hw1n[f * 32 + o];
        const float wv1 = hw1n[(f + 1) * 32 + o];
        a0 += wv0 * tileL[f * 52 + p2];
        a1 += wv0 * tileL[f * 52 + p2 + 1];
        a2 += wv1 * tileL[(f + 1) * 52 + p2];
        a3 += wv1 * tileL[(f + 1) * 52 + p2 + 1];
      }
      tile2[o * 52 + p2] = f2bf(a0 + a2);
      if (p2 + 1 < 49) tile2[o * 52 + p2 + 1] = f2bf(a1 + a3);
    }
    __syncthreads();

    short* outp = wcb + h * 16384 + n * 4096;
    for (int idx = tid; idx < 4096; idx += 256) {
      const int jj = idx & 7, ln = (idx >> 3) & 63;
      const int nt = (idx >> 9) & 1, kt = (idx >> 10) & 1;
      const int par = idx >> 11;
      const int k = kt * 32 + ((ln >> 4) << 3) + jj;
      const int oo = nt * 16 + (ln & 15);
      const int r = k >> 3, dlt = k & 7;
      const int j = par ? (dlt - 1) : dlt;
      short v = 0;
      if (r < 7 && j >= 0 && j < 7) v = tile2[oo * 52 + r * 7 + j];
      if (k == 56) v = f2bf(bias32[oo]);   // bias in dead K-slot
      outp[idx] = v;
    }
    return;
  }

  if (bid < 528) {            // ---- fw2 kt-tile transpose: K rows 32, N 256
    short* S = (short*)sm;               // [32][260]
    const int kt = bid - 512;
    const float* src = fw2 + kt * 8192;
    for (int q = tid; q < 2048; q += 256) {
      const int lin = q * 4;
      const int kk = lin >> 8, nn = lin & 255;
      st4bf(S + kk * 260 + nn, *(const float4*)(src + lin));
    }
    __syncthreads();
    short* dst = fw2s + kt * 8192;
    for (int q = tid; q < 8192; q += 256) {
      const int jj = q & 7, lane = (q >> 3) & 63, nt = q >> 9;
      const int kk = (lane >> 4) * 8 + jj, nn = nt * 16 + (lane & 15);
      dst[q] = S[kk * 260 + nn];
    }
    return;
  }

  if (bid < 530) {            // ---- fw1 transpose half X: K 32, N 256
    const int X = bid - 528;
    short* S = (short*)sm;               // [32][260]
    for (int q = tid; q < 2048; q += 256) {
      const int lin = q * 4;
      const int kk = lin >> 8, nn = lin & 255;
      st4bf(S + kk * 260 + nn, *(const float4*)(fw1 + kk * 512 + X * 256 + nn));
    }
    __syncthreads();
    for (int q = tid; q < 8192; q += 256) {
      const int jj = q & 7, lane = (q >> 3) & 63, ntl = q >> 9;
      const int kk = (lane >> 4) * 8 + jj, nn = ntl * 16 + (lane & 15);
      fw1s[X * 8192 + q] = S[kk * 260 + nn];
    }
    return;
  }

  {                           // ---- bid 530: fw3 transpose: K 256, N 32
    short* S = (short*)sm;               // [256][36]
    for (int q = tid; q < 2048; q += 256) {
      const int lin = q * 4;
      const int kk = lin >> 5, nn = lin & 31;
      st4bf(S + kk * 36 + nn, *(const float4*)(fw3 + lin));
    }
    __syncthreads();
    for (int q = tid; q < 8192; q += 256) {
      const int jj = q & 7, lane = (q >> 3) & 63;
      const int nt = (q >> 9) & 1, kt = q >> 10;
      const int kk = kt * 32 + (lane >> 4) * 8 + jj, nn = nt * 16 + (lane & 15);
      fw3s[q] = S[kk * 36 + nn];
    }
  }
}

// ---------------------------------------------------------------------------
// K23: DISCO conv (hw1-folded, bias-in-MFMA) + head-MLP tail + final MLP.
// grid (8,128,2), block 256, LDS 20384 B, cap 64 -> 8 blocks/CU (R9 A/B:
// cap-8-with-spill 75.8 < cap-7-spill-free 78.5; scratch traffic is free at
// 3% HBM util, the 8th block's latency hiding wins).
// R10:
//  * 1-deep tap-prefetch pipeline in phase A: i+1's gathers issue after i's
//    MFMAs, BEFORE the gelu epilogue -> per-wave in-order DS stream no longer
//    exposes ~120cy gather latency every iteration.
//  * zero-fill cut 20384B -> 160B guard only (sX fully staged-over, sM
//    write-before-read, row pads never read); its barrier merged away.
// LDS map: phase A sX [0,17920) + guard [17920,18080) + sM [18080,20384);
// phase B sT1h/sT2 [0,16896) alias sX (sM survives), sO f32 behind barrier.
// ---------------------------------------------------------------------------
__global__ __launch_bounds__(256, 8) void k23_fused(
    const float* __restrict__ x,    const short* __restrict__ wcb,
    const float* __restrict__ hw2,  const float* __restrict__ hb2,
    const short* __restrict__ fw1s, const short* __restrict__ fw2s,
    const short* __restrict__ fw3s,
    const float* __restrict__ fb1,  const float* __restrict__ fb2,
    const float* __restrict__ fb3,  float* __restrict__ outb) {
  __shared__ __align__(16) char smem[20384];
  short* sX = (short*)smem;                  // [32 ch][7 slots x 40]
  short* sM = (short*)(smem + 18080);        // [32][36] bf16

  const int tid = threadIdx.x;
  int w0, b, h, lin;
  tile_map(w0, b, h, lin);

  const int lane = tid & 63, lm = lane & 15, lq = lane >> 4;
  const int n = tid >> 6;  // wave == head in phase A
  const int idx16 = (lane ^ 16) << 2;        // bpermute byte indices
  const int idx32 = (lane ^ 32) << 2;
  const unsigned injm = (lq == 3) ? 0xFFFFu : 0u;   // 1.0-tap inject mask

  const float hb2n = hb2[n];

  // zero only the 160B guard (c=31's virtual slot-7 taps land here; must be
  // finite-zero). sX is fully overwritten by staging; sM is write-before-read.
  if (tid < 10) {
    int4 z; z.x = z.y = z.z = z.w = 0;
    ((int4*)(smem + 17920))[tid] = z;
  }

  // stage x tile as bf16; channel stride 280 shorts; row r -> slot
  // {0,2,4,6,1,3,5} (slot stride 40 shorts) for conflict-free gathers
#pragma unroll 1
  for (int r = 0; r < 7; ++r) {
    int hr = h - 3 + r; hr = hr < 0 ? 0 : (hr > 127 ? 127 : hr);
    const int slot = (r < 4) ? (2 * r) : (2 * r - 7);
    const float* __restrict__ xrow = x + (size_t)((b * 128 + hr) * 256) * 34;
    short* __restrict__ sxr = sX + slot * 40;
    for (int e = tid; e < 39 * 16; e += 256) {
      const int c2 = e & 15;
      const int wp = e >> 4;
      const int wr = (w0 - 3 + wp) & 255;
      const float2 v = *(const float2*)&xrow[wr * 34 + c2 * 2];
      short* dp = sxr + (c2 * 2) * 280 + wp;
      dp[0]   = f2bf_fast(v.x);
      dp[280] = f2bf_fast(v.y);
    }
  }
  __syncthreads();

  const int* tpB = (const int*)sX;

  // per-lane hw2 scale for this lane's 8 o-rows (par-invariant, hoisted)
  const float4 w0v = *(const float4*)(hw2 + n * 32 + lq * 4);
  const float4 w1v = *(const float4*)(hw2 + n * 32 + 16 + lq * 4);

  // ---- phase A: A=weights(rows=o, bias in k=56), B=taps -> D[o, pixel]
  // 1-deep software pipeline on the tap gathers.
#pragma unroll 1
  for (int par = 0; par < 2; ++par) {
    bfrag cw[2][2];
#pragma unroll
    for (int kt = 0; kt < 2; ++kt)
#pragma unroll
      for (int nt = 0; nt < 2; ++nt)
        cw[kt][nt] = *(const bfrag*)(wcb + h * 16384 + n * 4096 +
                         ((par * 2 + kt) * 2 + nt) * 512 + lane * 8);

    // prologue: gather taps for i=0
    int base0 = (n * 8) * 140 + lq * 40 + lm;
    bfi4 uc0, uc1, un0, un1;
    uc0.i.x = tpB[base0];      uc0.i.y = tpB[base0 + 1];
    uc0.i.z = tpB[base0 + 2];  uc0.i.w = tpB[base0 + 3];
    uc1.i.x = tpB[base0 + 20]; uc1.i.y = tpB[base0 + 21];
    uc1.i.z = tpB[base0 + 22]; uc1.i.w = tpB[base0 + 23];

#pragma unroll 1
    for (int i = 0; i < 8; ++i) {
      const int c = n * 8 + i;

      // inject 1.0 at K-slot 56 (lq==3, entry jj=0 of u1) -> bias row fires
      uc1.i.x = (int)(((unsigned)uc1.i.x & ~injm) | (0x3F80u & injm));

      ffrag h0 = {0.f, 0.f, 0.f, 0.f}, h1 = {0.f, 0.f, 0.f, 0.f};
      h0 = __builtin_amdgcn_mfma_f32_16x16x32_bf16(cw[0][0], uc0.b, h0, 0, 0, 0);
      h0 = __builtin_amdgcn_mfma_f32_16x16x32_bf16(cw[1][0], uc1.b, h0, 0, 0, 0);
      h1 = __builtin_amdgcn_mfma_f32_16x16x32_bf16(cw[0][1], uc0.b, h1, 0, 0, 0);
      h1 = __builtin_amdgcn_mfma_f32_16x16x32_bf16(cw[1][1], uc1.b, h1, 0, 0, 0);

      // prefetch i+1's taps NOW -> latency hides under the gelu epilogue
      if (i < 7) {
        const int nb = base0 + 140;
        un0.i.x = tpB[nb];      un0.i.y = tpB[nb + 1];
        un0.i.z = tpB[nb + 2];  un0.i.w = tpB[nb + 3];
        un1.i.x = tpB[nb + 20]; un1.i.y = tpB[nb + 21];
        un1.i.z = tpB[nb + 22]; un1.i.w = tpB[nb + 23];
      }

      // in-lane o-contraction (bias already in h), then 4-way lq reduce
      float s0 = gelu_f(h0[0]) * w0v.x;
      s0 += gelu_f(h0[1]) * w0v.y;
      s0 += gelu_f(h0[2]) * w0v.z;
      s0 += gelu_f(h0[3]) * w0v.w;
      float s1 = gelu_f(h1[0]) * w1v.x;
      s1 += gelu_f(h1[1]) * w1v.y;
      s1 += gelu_f(h1[2]) * w1v.z;
      s1 += gelu_f(h1[3]) * w1v.w;
      union { float f; int i; } sv, t1, t2;
      sv.f = s0 + s1;
      t1.i = __builtin_amdgcn_ds_bpermute(idx16, sv.i);
      sv.f += t1.f;
      t2.i = __builtin_amdgcn_ds_bpermute(idx32, sv.i);
      const float tot = sv.f + t2.f;

      const int p = 2 * lm + par;
      const float res = bf2f(sX[c * 280 + 243 + p]);  // center tap (slot 6)
      if (lq == 0) sM[p * 36 + c] = f2bf_fast(tot + hb2n + res);

      // rotate pipeline
      uc0 = un0; uc1 = un1; base0 += 140;
    }
  }
  __syncthreads();

  // ---- phase B: fused MLP 32->512(gelu)->256(gelu)->32 (+residual)
  short* sT1h = (short*)smem;
  short* sT2  = (short*)smem;
  float* sO   = (float*)smem;
  const int wave = n;
  const int koff = lq * 8;
  const int mt3 = wave & 1;
  const int nt3 = wave >> 1;
  const int col3 = nt3 * 16 + lm;
  const int pixg = (b * 128 + h) * 256 + w0;
  const int n0 = wave * 4;

  ffrag acc[2][4];
#pragma unroll
  for (int mt = 0; mt < 2; ++mt)
#pragma unroll
    for (int ni = 0; ni < 4; ++ni) acc[mt][ni] = ffrag{0.f, 0.f, 0.f, 0.f};
  const short* w2base = fw2s + n0 * 512 + lane * 8;

#pragma unroll 1
  for (int H = 0; H < 2; ++H) {
    // layer 1, half H: A=fw1 frag (rows=ff1 cols), B=sM (cols=pixels)
#pragma unroll
    for (int ni = 0; ni < 4; ++ni) {
      const bfrag b1f = *(const bfrag*)(fw1s +
                          (H * 16 + wave * 4 + ni) * 512 + lane * 8);
      const int ntl = wave * 4 + ni;
      const float4 fb1v = *(const float4*)(fb1 + H * 256 + ntl * 16 + lq * 4);
#pragma unroll
      for (int mt = 0; mt < 2; ++mt) {
        const bfrag aFm = *(const bfrag*)(sM + (mt * 16 + lm) * 36 + koff);
        ffrag cc = {0.f, 0.f, 0.f, 0.f};
        cc = __builtin_amdgcn_mfma_f32_16x16x32_bf16(b1f, aFm, cc, 0, 0, 0);
        // D rows = 4 consecutive ff1 cols, col = pixel mt*16+lm -> b64 store
        int2 wv;
        wv.x = pkbf(gelu_f(cc[0] + fb1v.x), gelu_f(cc[1] + fb1v.y));
        wv.y = pkbf(gelu_f(cc[2] + fb1v.z), gelu_f(cc[3] + fb1v.w));
        *(int2*)(sT1h + (mt * 16 + lm) * 264 + ntl * 16 + lq * 4) = wv;
      }
    }
    __syncthreads();

    // layer 2: A=fw2 frag (rows=ff2 cols), B=sT1h (cols=pixels)
#pragma unroll 1
    for (int kt = 0; kt < 8; ++kt) {
      const bfrag a0 = *(const bfrag*)(sT1h + lm * 264 + kt * 32 + koff);
      const bfrag a1 = *(const bfrag*)(sT1h + (16 + lm) * 264 + kt * 32 + koff);
#pragma unroll
      for (int np = 0; np < 2; ++np) {
        const bfrag bv0 = *(const bfrag*)(w2base + (H * 8 + kt) * 8192 + (2 * np) * 512);
        const bfrag bv1 = *(const bfrag*)(w2base + (H * 8 + kt) * 8192 + (2 * np + 1) * 512);
        acc[0][2 * np]     = __builtin_amdgcn_mfma_f32_16x16x32_bf16(bv0, a0, acc[0][2 * np], 0, 0, 0);
        acc[1][2 * np]     = __builtin_amdgcn_mfma_f32_16x16x32_bf16(bv0, a1, acc[1][2 * np], 0, 0, 0);
        acc[0][2 * np + 1] = __builtin_amdgcn_mfma_f32_16x16x32_bf16(bv1, a0, acc[0][2 * np + 1], 0, 0, 0);
        acc[1][2 * np + 1] = __builtin_amdgcn_mfma_f32_16x16x32_bf16(bv1, a1, acc[1][2 * np + 1], 0, 0, 0);
      }
    }
    __syncthreads();   // before next half overwrites sT1h
  }

  // t2 epilogue: acc rows = 4 consecutive ff2 cols, col = pixel -> b64 store
#pragma unroll
  for (int mt = 0; mt < 2; ++mt)
#pragma unroll
    for (int ni = 0; ni < 4; ++ni) {
      const float4 fb2v = *(const float4*)(fb2 + (n0 + ni) * 16 + lq * 4);
      int2 wv;
      wv.x = pkbf(gelu_f(acc[mt][ni][0] + fb2v.x), gelu_f(acc[mt][ni][1] + fb2v.y));
      wv.y = pkbf(gelu_f(acc[mt][ni][2] + fb2v.z), gelu_f(acc[mt][ni][3] + fb2v.w));
      *(int2*)(sT2 + (mt * 16 + lm) * 264 + (n0 + ni) * 16 + lq * 4) = wv;
    }
  __syncthreads();

  // layer 3 (reads sT2; D rows = pixels as before)
  ffrag c3 = {0.f, 0.f, 0.f, 0.f};
  const short* sA3 = sT2 + (mt3 * 16 + lm) * 264 + koff;
#pragma unroll
  for (int kt = 0; kt < 8; ++kt) {
    const bfrag a = *(const bfrag*)(sA3 + kt * 32);
    const bfrag bw = *(const bfrag*)(fw3s + nt3 * 512 + kt * 1024 + lane * 8);
    c3 = __builtin_amdgcn_mfma_f32_16x16x32_bf16(a, bw, c3, 0, 0, 0);
  }
  __syncthreads();   // all sT2 reads done before sO overwrite
  {
    const float bias = fb3[col3];
#pragma unroll
    for (int r = 0; r < 4; ++r) {
      const int row = mt3 * 16 + lq * 4 + r;
      const float res = bf2f(sM[row * 36 + col3]);
      sO[row * 34 + col3] = c3[r] + bias + res;
    }
  }
  if (tid < 32) {   // sincos passthrough (x row L2-hot)
    const float2 scv =
        *(const float2*)&x[(size_t)(((b * 128 + h) * 256 + w0 + tid)) * 34 + 32];
    sO[tid * 34 + 32] = scv.x;
    sO[tid * 34 + 33] = scv.y;
  }
  __syncthreads();
  {
    const float4* sp = (const float4*)sO;           // 1088 floats = 272 f4
    float4* dp = (float4*)(outb + (size_t)pixg * 34);
    for (int e = tid; e < 272; e += 256) dp[e] = sp[e];
  }
}

// ---------------------------------------------------------------------------
extern "C" void kernel_launch(void* const* d_in, const int* in_sizes, int n_in,
                              void* d_out, int out_size, void* d_ws, size_t ws_size,
                              hipStream_t stream) {
  const float* x   = (const float*)d_in[0];
  const float* psi = (const float*)d_in[1];
  const float* dw  = (const float*)d_in[2];
  const float* db  = (const float*)d_in[3];
  const float* hw1 = (const float*)d_in[4];
  const float* hb1 = (const float*)d_in[5];
  const float* hw2 = (const float*)d_in[6];
  const float* hb2 = (const float*)d_in[7];
  const float* fw1 = (const float*)d_in[8];
  const float* fb1 = (const float*)d_in[9];
  const float* fw2 = (const float*)d_in[10];
  const float* fb2 = (const float*)d_in[11];
  const float* fw3 = (const float*)d_in[12];
  const float* fb3 = (const float*)d_in[13];
  float* outb = (float*)d_out;

  // workspace (~4.5 MB)
  short* wcb  = (short*)d_ws;        // 128*16384 = 2097152 shorts
  short* fw1s = wcb + 2097152;       // 16384
  short* fw2s = fw1s + 16384;        // 131072
  short* fw3s = fw2s + 131072;       // 8192

  hipLaunchKernelGGL(k01_prep, dim3(531), dim3(256), 0, stream,
                     psi, dw, db, fw1, fw2, fw3, hw1, hb1,
                     wcb, fw1s, fw2s, fw3s);
  hipLaunchKernelGGL(k23_fused, dim3(8, 128, 2), dim3(256), 0, stream,
                     x, wcb, hw2, hb2,
                     fw1s, fw2s, fw3s, fb1, fb2, fb3, outb);
}

// Round 11
// 164.315 us; speedup vs baseline: 1.0184x; 1.0146x over previous
//
#include <hip/hip_runtime.h>
#include <math.h>

// Problem constants
// B=2, H=128, W=256, MD=34, LD=32, NH=4, HD=8, SH=64, K=25, P=7, R=3,
// FF1=512, FF2=256

typedef __attribute__((ext_vector_type(8))) short bfrag;    // 8 bf16 = 4 VGPR
typedef __attribute__((ext_vector_type(4))) float ffrag;    // 4 f32 acc
typedef __attribute__((ext_vector_type(4))) short short4v;  // 8B

union bfi4 { int4 i; bfrag b; };

// Fast tanh-form GELU (~7 VALU ops, |err| vs erf-GELU ~3e-3)
__device__ __forceinline__ float gelu_f(float v) {
  const float z = v * (2.3022077484f + 0.1029451564f * v * v);  // log2e folded
  const float e = __builtin_amdgcn_exp2f(-z);
  return v * __builtin_amdgcn_rcpf(1.0f + e);
}

// exact RNE (cold paths: weight prep)
__device__ __forceinline__ short f2bf(float f) {
  union { float f; unsigned u; } v; v.f = f;
  unsigned r = (v.u + 0x7fffu + ((v.u >> 16) & 1u)) >> 16;
  return (short)r;
}

// round-half-up (2 VALU ops)
__device__ __forceinline__ short f2bf_fast(float f) {
  union { float f; unsigned u; } v; v.f = f;
  return (short)((v.u + 0x8000u) >> 16);
}

__device__ __forceinline__ float bf2f(short s) {
  union { float f; unsigned u; } v;
  v.u = ((unsigned)(unsigned short)s) << 16;
  return v.f;
}

// pack two f32 -> bf16 pair in one dword: (bf(b)<<16)|bf(a); 3 VALU ops
__device__ __forceinline__ int pkbf(float a, float b) {
  union { float f; unsigned u; } va, vb; va.f = a; vb.f = b;
  return (int)__builtin_amdgcn_perm(vb.u + 0x8000u, va.u + 0x8000u, 0x07060302u);
}

// staged bf16 short4 store helper
__device__ __forceinline__ void st4bf(short* p, float4 v) {
  short4v s;
  s[0] = f2bf(v.x); s[1] = f2bf(v.y); s[2] = f2bf(v.z); s[3] = f2bf(v.w);
  *(short4v*)p = s;
}

// XCD-aware bijective remap (8 XCDs x 256 slots; 16 slots share one h)
__device__ __forceinline__ void tile_map(int& w0, int& b, int& h, int& lin) {
  lin  = blockIdx.x + (blockIdx.y << 3) + (blockIdx.z << 10);
  const int xcd  = lin & 7;
  const int slot = lin >> 3;
  w0 = (slot & 7) * 32;
  b  = (slot >> 3) & 1;
  h  = (xcd << 4) | (slot >> 4);
}

// ---------------------------------------------------------------------------
// K01: weight prep. REWRITTEN for parallelism: the old 512-block version was
// ~80-85 us ALL SESSION (half the wall; hidden because it never made top-5):
// 2 blocks/CU, and 13x25 serial UNIFORM psi s_loads per wave with 8 waves/CU
// of latency hiding. Now:
//  * bid 0..1023: one block per (h, n, G=o-half). psi rows for this h staged
//    cooperatively into LDS (coalesced; kills the s_load chains); hw1 half
//    staged; tileL recomputed per block (78K MAC, ~2us chip-wide total);
//    tile2/bias/emission cover only this half's 16 o-values. Fragment nt bit
//    == G, so emission ranges are disjoint. 4 blocks/CU, 16 waves/CU.
//  * bid 1024..1039: fw2 kt transposes. 1040..1041: fw1 halves. 1042: fw3.
// Head-MLP bias still baked into dead K-slot 56 of the fragments.
// ---------------------------------------------------------------------------
__global__ __launch_bounds__(256) void k01_prep(
    const float* __restrict__ psi, const float* __restrict__ dw,
    const float* __restrict__ db,
    const float* __restrict__ fw1, const float* __restrict__ fw2,
    const float* __restrict__ fw3, const float* __restrict__ hw1,
    const float* __restrict__ hb1,
    short* __restrict__ wcb, short* __restrict__ fw1s,
    short* __restrict__ fw2s, short* __restrict__ fw3s) {
  __shared__ __align__(16) char sm[24832];
  const int bid = blockIdx.x;
  const int tid = threadIdx.x;

  if (bid < 1024) {           // ---- fused conv+MLP1 fragments per (h, n, G)
    float* psL    = (float*)sm;               // [25][52] f32 =  5200 B
    float* tileL  = (float*)(sm + 5200);      // [64][52] f32 = 13312 B
    float* hw1h   = (float*)(sm + 18512);     // [64][17] f32 =  4352 B
    short* tile2  = (short*)(sm + 22864);     // [16][52] bf16 = 1664 B
    float* bias16 = (float*)(sm + 24528);     // [16] f32     =    64 B
    const int h = bid >> 3;
    const int n = (bid >> 1) & 3;
    const int G = bid & 1;
    const int lane = tid & 63;
    const int w = __builtin_amdgcn_readfirstlane(tid >> 6);

    // stage psi rows for this h (25 x 49 floats, coalesced segments)
    for (int e = tid; e < 1600; e += 256) {
      const int kk = e >> 6, p = e & 63;
      if (p < 49) psL[kk * 52 + p] = psi[kk * 6272 + h * 49 + p];
    }
    // stage this (n, G) hw1 half: [64 f][16 o]
    for (int e = tid; e < 1024; e += 256) {
      const int f = e >> 4, o = e & 15;
      hw1h[f * 17 + o] = hw1[n * 2048 + f * 32 + G * 16 + o];
    }

    float dwreg[25];
#pragma unroll
    for (int kk = 0; kk < 25; ++kk) dwreg[kk] = dw[lane * 25 + kk];
    __syncthreads();

    // tileL[f][p] = sum_k dw[f,k]*psL[k][p]  (lane=f; psL reads broadcast)
    const int p0 = w * 13;
    const int pend = (p0 + 13 < 49) ? (p0 + 13) : 49;
#pragma unroll 1
    for (int p = p0; p < pend; ++p) {
      float ae = 0.f, ao = 0.f;           // 2 chains
#pragma unroll
      for (int kk = 0; kk < 24; kk += 2) {
        ae += dwreg[kk]     * psL[kk * 52 + p];
        ao += dwreg[kk + 1] * psL[(kk + 1) * 52 + p];
      }
      ae += dwreg[24] * psL[24 * 52 + p];
      tileL[lane * 52 + p] = ae + ao;
    }
    __syncthreads();

    // bias16[o] = hb1[n][G*16+o] + sum_s hw1h[s][o]*db[s]   (exact f32)
    if (tid >= 240) {
      const int o = tid - 240;
      float acc = hb1[n * 32 + G * 16 + o];
#pragma unroll 4
      for (int s = 0; s < 64; ++s) acc += hw1h[s * 17 + o] * db[s];
      bias16[o] = acc;
    }

    // tile2[o][p2,p2+1] = sum_f hw1h[f][o] * tileL[f][p2,p2+1]
    const int o = tid & 15;
#pragma unroll 1
    for (int pp = tid >> 4; pp < 25; pp += 16) {
      const int p2 = pp * 2;
      float a0 = 0.f, a1 = 0.f, a2 = 0.f, a3 = 0.f;   // 4 chains
#pragma unroll 4
      for (int f = 0; f < 64; f += 2) {
        const float wv0 = hw1h[f * 17 + o];
        const float wv1 = hw1h[(f + 1) * 17 + o];
        a0 += wv0 * tileL[f * 52 + p2];
        a1 += wv0 * tileL[f * 52 + p2 + 1];
        a2 += wv1 * tileL[(f + 1) * 52 + p2];
        a3 += wv1 * tileL[(f + 1) * 52 + p2 + 1];
      }
      tile2[o * 52 + p2] = f2bf(a0 + a2);
      if (p2 + 1 < 49) tile2[o * 52 + p2 + 1] = f2bf(a1 + a3);
    }
    __syncthreads();

    // emission: this half's 2048 shorts (nt bit == G)
    short* outp = wcb + h * 16384 + n * 4096;
    for (int q = tid; q < 2048; q += 256) {
      const int sub = q & 511;
      const int pk = q >> 9;            // par*2 + kt
      const int par = pk >> 1, kt = pk & 1;
      const int jj = sub & 7, ln = (sub >> 3) & 63;
      const int k = kt * 32 + ((ln >> 4) << 3) + jj;
      const int ol = ln & 15;
      const int r = k >> 3, dlt = k & 7;
      const int j = par ? (dlt - 1) : dlt;
      short v = 0;
      if (r < 7 && j >= 0 && j < 7) v = tile2[ol * 52 + r * 7 + j];
      if (k == 56) v = f2bf(bias16[ol]);   // bias in dead K-slot
      outp[par * 2048 + kt * 1024 + G * 512 + sub] = v;
    }
    return;
  }

  if (bid < 1040) {           // ---- fw2 kt-tile transpose: K rows 32, N 256
    short* S = (short*)sm;               // [32][260]
    const int kt = bid - 1024;
    const float* src = fw2 + kt * 8192;
    for (int q = tid; q < 2048; q += 256) {
      const int lin = q * 4;
      const int kk = lin >> 8, nn = lin & 255;
      st4bf(S + kk * 260 + nn, *(const float4*)(src + lin));
    }
    __syncthreads();
    short* dst = fw2s + kt * 8192;
    for (int q = tid; q < 8192; q += 256) {
      const int jj = q & 7, lane = (q >> 3) & 63, nt = q >> 9;
      const int kk = (lane >> 4) * 8 + jj, nn = nt * 16 + (lane & 15);
      dst[q] = S[kk * 260 + nn];
    }
    return;
  }

  if (bid < 1042) {           // ---- fw1 transpose half X: K 32, N 256
    const int X = bid - 1040;
    short* S = (short*)sm;               // [32][260]
    for (int q = tid; q < 2048; q += 256) {
      const int lin = q * 4;
      const int kk = lin >> 8, nn = lin & 255;
      st4bf(S + kk * 260 + nn, *(const float4*)(fw1 + kk * 512 + X * 256 + nn));
    }
    __syncthreads();
    for (int q = tid; q < 8192; q += 256) {
      const int jj = q & 7, lane = (q >> 3) & 63, ntl = q >> 9;
      const int kk = (lane >> 4) * 8 + jj, nn = ntl * 16 + (lane & 15);
      fw1s[X * 8192 + q] = S[kk * 260 + nn];
    }
    return;
  }

  {                           // ---- bid 1042: fw3 transpose: K 256, N 32
    short* S = (short*)sm;               // [256][36]
    for (int q = tid; q < 2048; q += 256) {
      const int lin = q * 4;
      const int kk = lin >> 5, nn = lin & 31;
      st4bf(S + kk * 36 + nn, *(const float4*)(fw3 + lin));
    }
    __syncthreads();
    for (int q = tid; q < 8192; q += 256) {
      const int jj = q & 7, lane = (q >> 3) & 63;
      const int nt = (q >> 9) & 1, kt = q >> 10;
      const int kk = kt * 32 + (lane >> 4) * 8 + jj, nn = nt * 16 + (lane & 15);
      fw3s[q] = S[kk * 36 + nn];
    }
  }
}

// ---------------------------------------------------------------------------
// K23: DISCO conv (hw1-folded, bias-in-MFMA) + head-MLP tail + final MLP.
// grid (8,128,2), block 256, LDS 20384 B, cap 64 -> 8 blocks/CU.
// R11 = R8 body exactly (R10's tap-prefetch pipeline REVERTED: +16 live regs
// pushed spill deeper, 75.8 -> 80.3; spill-with-8-blocks remains the best
// point per the R9 A/B) + guard-only zero-fill kept from R10.
// LDS map: phase A sX [0,17920) + guard [17920,18080) + sM [18080,20384);
// phase B sT1h/sT2 [0,16896) alias sX (sM survives), sO f32 behind barrier.
// ---------------------------------------------------------------------------
__global__ __launch_bounds__(256, 8) void k23_fused(
    const float* __restrict__ x,    const short* __restrict__ wcb,
    const float* __restrict__ hw2,  const float* __restrict__ hb2,
    const short* __restrict__ fw1s, const short* __restrict__ fw2s,
    const short* __restrict__ fw3s,
    const float* __restrict__ fb1,  const float* __restrict__ fb2,
    const float* __restrict__ fb3,  float* __restrict__ outb) {
  __shared__ __align__(16) char smem[20384];
  short* sX = (short*)smem;                  // [32 ch][7 slots x 40]
  short* sM = (short*)(smem + 18080);        // [32][36] bf16

  const int tid = threadIdx.x;
  int w0, b, h, lin;
  tile_map(w0, b, h, lin);

  const int lane = tid & 63, lm = lane & 15, lq = lane >> 4;
  const int n = tid >> 6;  // wave == head in phase A
  const int idx16 = (lane ^ 16) << 2;        // bpermute byte indices
  const int idx32 = (lane ^ 32) << 2;
  const unsigned injm = (lq == 3) ? 0xFFFFu : 0u;   // 1.0-tap inject mask

  const float hb2n = hb2[n];

  // zero only the 160B guard (c=31's virtual slot-7 taps land here; must be
  // finite-zero). sX is fully overwritten by staging; sM is write-before-read.
  if (tid < 10) {
    int4 z; z.x = z.y = z.z = z.w = 0;
    ((int4*)(smem + 17920))[tid] = z;
  }

  // stage x tile as bf16; channel stride 280 shorts; row r -> slot
  // {0,2,4,6,1,3,5} (slot stride 40 shorts) for conflict-free gathers
#pragma unroll 1
  for (int r = 0; r < 7; ++r) {
    int hr = h - 3 + r; hr = hr < 0 ? 0 : (hr > 127 ? 127 : hr);
    const int slot = (r < 4) ? (2 * r) : (2 * r - 7);
    const float* __restrict__ xrow = x + (size_t)((b * 128 + hr) * 256) * 34;
    short* __restrict__ sxr = sX + slot * 40;
    for (int e = tid; e < 39 * 16; e += 256) {
      const int c2 = e & 15;
      const int wp = e >> 4;
      const int wr = (w0 - 3 + wp) & 255;
      const float2 v = *(const float2*)&xrow[wr * 34 + c2 * 2];
      short* dp = sxr + (c2 * 2) * 280 + wp;
      dp[0]   = f2bf_fast(v.x);
      dp[280] = f2bf_fast(v.y);
    }
  }
  __syncthreads();

  const int* tpB = (const int*)sX;

  // per-lane hw2 scale for this lane's 8 o-rows (par-invariant, hoisted)
  const float4 w0v = *(const float4*)(hw2 + n * 32 + lq * 4);
  const float4 w1v = *(const float4*)(hw2 + n * 32 + 16 + lq * 4);

  // ---- phase A: A=weights(rows=o, bias in k=56), B=taps -> D[o, pixel]
#pragma unroll 1
  for (int par = 0; par < 2; ++par) {
    bfrag cw[2][2];
#pragma unroll
    for (int kt = 0; kt < 2; ++kt)
#pragma unroll
      for (int nt = 0; nt < 2; ++nt)
        cw[kt][nt] = *(const bfrag*)(wcb + h * 16384 + n * 4096 +
                         ((par * 2 + kt) * 2 + nt) * 512 + lane * 8);

#pragma unroll 1
    for (int i = 0; i < 8; ++i) {
      const int c = n * 8 + i;

      // tap B-frags: lane lm = pixel; u0 rows 0-3 (slots 2lq),
      // u1 rows 4-7 (slots 2lq+1)
      const int base0 = c * 140 + lq * 40 + lm;
      bfi4 u0, u1;
      u0.i.x = tpB[base0];      u0.i.y = tpB[base0 + 1];
      u0.i.z = tpB[base0 + 2];  u0.i.w = tpB[base0 + 3];
      u1.i.x = tpB[base0 + 20]; u1.i.y = tpB[base0 + 21];
      u1.i.z = tpB[base0 + 22]; u1.i.w = tpB[base0 + 23];
      // inject 1.0 at K-slot 56 (lq==3, entry jj=0 of u1) -> bias row fires
      u1.i.x = (int)(((unsigned)u1.i.x & ~injm) | (0x3F80u & injm));

      ffrag h0 = {0.f, 0.f, 0.f, 0.f}, h1 = {0.f, 0.f, 0.f, 0.f};
      h0 = __builtin_amdgcn_mfma_f32_16x16x32_bf16(cw[0][0], u0.b, h0, 0, 0, 0);
      h0 = __builtin_amdgcn_mfma_f32_16x16x32_bf16(cw[1][0], u1.b, h0, 0, 0, 0);
      h1 = __builtin_amdgcn_mfma_f32_16x16x32_bf16(cw[0][1], u0.b, h1, 0, 0, 0);
      h1 = __builtin_amdgcn_mfma_f32_16x16x32_bf16(cw[1][1], u1.b, h1, 0, 0, 0);

      // in-lane o-contraction (bias already in h), then 4-way lq reduce
      float s0 = gelu_f(h0[0]) * w0v.x;
      s0 += gelu_f(h0[1]) * w0v.y;
      s0 += gelu_f(h0[2]) * w0v.z;
      s0 += gelu_f(h0[3]) * w0v.w;
      float s1 = gelu_f(h1[0]) * w1v.x;
      s1 += gelu_f(h1[1]) * w1v.y;
      s1 += gelu_f(h1[2]) * w1v.z;
      s1 += gelu_f(h1[3]) * w1v.w;
      union { float f; int i; } sv, t1, t2;
      sv.f = s0 + s1;
      t1.i = __builtin_amdgcn_ds_bpermute(idx16, sv.i);
      sv.f += t1.f;
      t2.i = __builtin_amdgcn_ds_bpermute(idx32, sv.i);
      const float tot = sv.f + t2.f;

      const int p = 2 * lm + par;
      const float res = bf2f(sX[c * 280 + 243 + p]);  // center tap (slot 6)
      if (lq == 0) sM[p * 36 + c] = f2bf_fast(tot + hb2n + res);
    }
  }
  __syncthreads();

  // ---- phase B: fused MLP 32->512(gelu)->256(gelu)->32 (+residual)
  short* sT1h = (short*)smem;
  short* sT2  = (short*)smem;
  float* sO   = (float*)smem;
  const int wave = n;
  const int koff = lq * 8;
  const int mt3 = wave & 1;
  const int nt3 = wave >> 1;
  const int col3 = nt3 * 16 + lm;
  const int pixg = (b * 128 + h) * 256 + w0;
  const int n0 = wave * 4;

  ffrag acc[2][4];
#pragma unroll
  for (int mt = 0; mt < 2; ++mt)
#pragma unroll
    for (int ni = 0; ni < 4; ++ni) acc[mt][ni] = ffrag{0.f, 0.f, 0.f, 0.f};
  const short* w2base = fw2s + n0 * 512 + lane * 8;

#pragma unroll 1
  for (int H = 0; H < 2; ++H) {
    // layer 1, half H: A=fw1 frag (rows=ff1 cols), B=sM (cols=pixels)
#pragma unroll
    for (int ni = 0; ni < 4; ++ni) {
      const bfrag b1f = *(const bfrag*)(fw1s +
                          (H * 16 + wave * 4 + ni) * 512 + lane * 8);
      const int ntl = wave * 4 + ni;
      const float4 fb1v = *(const float4*)(fb1 + H * 256 + ntl * 16 + lq * 4);
#pragma unroll
      for (int mt = 0; mt < 2; ++mt) {
        const bfrag aFm = *(const bfrag*)(sM + (mt * 16 + lm) * 36 + koff);
        ffrag cc = {0.f, 0.f, 0.f, 0.f};
        cc = __builtin_amdgcn_mfma_f32_16x16x32_bf16(b1f, aFm, cc, 0, 0, 0);
        // D rows = 4 consecutive ff1 cols, col = pixel mt*16+lm -> b64 store
        int2 wv;
        wv.x = pkbf(gelu_f(cc[0] + fb1v.x), gelu_f(cc[1] + fb1v.y));
        wv.y = pkbf(gelu_f(cc[2] + fb1v.z), gelu_f(cc[3] + fb1v.w));
        *(int2*)(sT1h + (mt * 16 + lm) * 264 + ntl * 16 + lq * 4) = wv;
      }
    }
    __syncthreads();

    // layer 2: A=fw2 frag (rows=ff2 cols), B=sT1h (cols=pixels)
#pragma unroll 1
    for (int kt = 0; kt < 8; ++kt) {
      const bfrag a0 = *(const bfrag*)(sT1h + lm * 264 + kt * 32 + koff);
      const bfrag a1 = *(const bfrag*)(sT1h + (16 + lm) * 264 + kt * 32 + koff);
#pragma unroll
      for (int np = 0; np < 2; ++np) {
        const bfrag bv0 = *(const bfrag*)(w2base + (H * 8 + kt) * 8192 + (2 * np) * 512);
        const bfrag bv1 = *(const bfrag*)(w2base + (H * 8 + kt) * 8192 + (2 * np + 1) * 512);
        acc[0][2 * np]     = __builtin_amdgcn_mfma_f32_16x16x32_bf16(bv0, a0, acc[0][2 * np], 0, 0, 0);
        acc[1][2 * np]     = __builtin_amdgcn_mfma_f32_16x16x32_bf16(bv0, a1, acc[1][2 * np], 0, 0, 0);
        acc[0][2 * np + 1] = __builtin_amdgcn_mfma_f32_16x16x32_bf16(bv1, a0, acc[0][2 * np + 1], 0, 0, 0);
        acc[1][2 * np + 1] = __builtin_amdgcn_mfma_f32_16x16x32_bf16(bv1, a1, acc[1][2 * np + 1], 0, 0, 0);
      }
    }
    __syncthreads();   // before next half overwrites sT1h
  }

  // t2 epilogue: acc rows = 4 consecutive ff2 cols, col = pixel -> b64 store
#pragma unroll
  for (int mt = 0; mt < 2; ++mt)
#pragma unroll
    for (int ni = 0; ni < 4; ++ni) {
      const float4 fb2v = *(const float4*)(fb2 + (n0 + ni) * 16 + lq * 4);
      int2 wv;
      wv.x = pkbf(gelu_f(acc[mt][ni][0] + fb2v.x), gelu_f(acc[mt][ni][1] + fb2v.y));
      wv.y = pkbf(gelu_f(acc[mt][ni][2] + fb2v.z), gelu_f(acc[mt][ni][3] + fb2v.w));
      *(int2*)(sT2 + (mt * 16 + lm) * 264 + (n0 + ni) * 16 + lq * 4) = wv;
    }
  __syncthreads();

  // layer 3 (reads sT2; D rows = pixels as before)
  ffrag c3 = {0.f, 0.f, 0.f, 0.f};
  const short* sA3 = sT2 + (mt3 * 16 + lm) * 264 + koff;
#pragma unroll
  for (int kt = 0; kt < 8; ++kt) {
    const bfrag a = *(const bfrag*)(sA3 + kt * 32);
    const bfrag bw = *(const bfrag*)(fw3s + nt3 * 512 + kt * 1024 + lane * 8);
    c3 = __builtin_amdgcn_mfma_f32_16x16x32_bf16(a, bw, c3, 0, 0, 0);
  }
  __syncthreads();   // all sT2 reads done before sO overwrite
  {
    const float bias = fb3[col3];
#pragma unroll
    for (int r = 0; r < 4; ++r) {
      const int row = mt3 * 16 + lq * 4 + r;
      const float res = bf2f(sM[row * 36 + col3]);
      sO[row * 34 + col3] = c3[r] + bias + res;
    }
  }
  if (tid < 32) {   // sincos passthrough (x row L2-hot)
    const float2 scv =
        *(const float2*)&x[(size_t)(((b * 128 + h) * 256 + w0 + tid)) * 34 + 32];
    sO[tid * 34 + 32] = scv.x;
    sO[tid * 34 + 33] = scv.y;
  }
  __syncthreads();
  {
    const float4* sp = (const float4*)sO;           // 1088 floats = 272 f4
    float4* dp = (float4*)(outb + (size_t)pixg * 34);
    for (int e = tid; e < 272; e += 256) dp[e] = sp[e];
  }
}

// ---------------------------------------------------------------------------
extern "C" void kernel_launch(void* const* d_in, const int* in_sizes, int n_in,
                              void* d_out, int out_size, void* d_ws, size_t ws_size,
                              hipStream_t stream) {
  const float* x   = (const float*)d_in[0];
  const float* psi = (const float*)d_in[1];
  const float* dw  = (const float*)d_in[2];
  const float* db  = (const float*)d_in[3];
  const float* hw1 = (const float*)d_in[4];
  const float* hb1 = (const float*)d_in[5];
  const float* hw2 = (const float*)d_in[6];
  const float* hb2 = (const float*)d_in[7];
  const float* fw1 = (const float*)d_in[8];
  const float* fb1 = (const float*)d_in[9];
  const float* fw2 = (const float*)d_in[10];
  const float* fb2 = (const float*)d_in[11];
  const float* fw3 = (const float*)d_in[12];
  const float* fb3 = (const float*)d_in[13];
  float* outb = (float*)d_out;

  // workspace (~4.5 MB)
  short* wcb  = (short*)d_ws;        // 128*16384 = 2097152 shorts
  short* fw1s = wcb + 2097152;       // 16384
  short* fw2s = fw1s + 16384;        // 131072
  short* fw3s = fw2s + 131072;       // 8192

  hipLaunchKernelGGL(k01_prep, dim3(1043), dim3(256), 0, stream,
                     psi, dw, db, fw1, fw2, fw3, hw1, hb1,
                     wcb, fw1s, fw2s, fw3s);
  hipLaunchKernelGGL(k23_fused, dim3(8, 128, 2), dim3(256), 0, stream,
                     x, wcb, hw2, hb2,
                     fw1s, fw2s, fw3s, fb1, fb2, fb3, outb);
}

// Round 13
// 163.643 us; speedup vs baseline: 1.0226x; 1.0041x over previous
//
#include <hip/hip_runtime.h>
#include <math.h>

// Problem constants
// B=2, H=128, W=256, MD=34, LD=32, NH=4, HD=8, SH=64, K=25, P=7, R=3,
// FF1=512, FF2=256

typedef __attribute__((ext_vector_type(8))) short bfrag;    // 8 bf16 = 4 VGPR
typedef __attribute__((ext_vector_type(4))) float ffrag;    // 4 f32 acc
typedef __attribute__((ext_vector_type(4))) short short4v;  // 8B

union bfi4 { int4 i; bfrag b; };

// Fast tanh-form GELU (~7 VALU ops, |err| vs erf-GELU ~3e-3)
__device__ __forceinline__ float gelu_f(float v) {
  const float z = v * (2.3022077484f + 0.1029451564f * v * v);  // log2e folded
  const float e = __builtin_amdgcn_exp2f(-z);
  return v * __builtin_amdgcn_rcpf(1.0f + e);
}

// exact RNE (cold paths: weight prep)
__device__ __forceinline__ short f2bf(float f) {
  union { float f; unsigned u; } v; v.f = f;
  unsigned r = (v.u + 0x7fffu + ((v.u >> 16) & 1u)) >> 16;
  return (short)r;
}

// round-half-up (2 VALU ops)
__device__ __forceinline__ short f2bf_fast(float f) {
  union { float f; unsigned u; } v; v.f = f;
  return (short)((v.u + 0x8000u) >> 16);
}

__device__ __forceinline__ float bf2f(short s) {
  union { float f; unsigned u; } v;
  v.u = ((unsigned)(unsigned short)s) << 16;
  return v.f;
}

// pack two f32 -> bf16 pair in one dword: (bf(b)<<16)|bf(a); 3 VALU ops
__device__ __forceinline__ int pkbf(float a, float b) {
  union { float f; unsigned u; } va, vb; va.f = a; vb.f = b;
  return (int)__builtin_amdgcn_perm(vb.u + 0x8000u, va.u + 0x8000u, 0x07060302u);
}

// staged bf16 short4 store helper
__device__ __forceinline__ void st4bf(short* p, float4 v) {
  short4v s;
  s[0] = f2bf(v.x); s[1] = f2bf(v.y); s[2] = f2bf(v.z); s[3] = f2bf(v.w);
  *(short4v*)p = s;
}

// XCD-aware bijective remap (8 XCDs x 256 slots; 16 slots share one h)
__device__ __forceinline__ void tile_map(int& w0, int& b, int& h, int& lin) {
  lin  = blockIdx.x + (blockIdx.y << 3) + (blockIdx.z << 10);
  const int xcd  = lin & 7;
  const int slot = lin >> 3;
  w0 = (slot & 7) * 32;
  b  = (slot >> 3) & 1;
  h  = (xcd << 4) | (slot >> 4);
}

// ---------------------------------------------------------------------------
// K01: weight prep (R11 version).
//  * bid 0..1023: one block per (h, n, G=o-half). psi rows for this h staged
//    cooperatively into LDS; hw1 half staged; tileL recomputed per block;
//    tile2/bias/emission cover only this half's 16 o-values. Fragment nt bit
//    == G, so emission ranges are disjoint. 4 blocks/CU, 16 waves/CU.
//  * bid 1024..1039: fw2 kt transposes. 1040..1041: fw1 halves. 1042: fw3.
// Head-MLP bias baked into dead K-slot 56 of the fragments.
// NOTE (R12 post-mortem): hipLaunchCooperativeKernel silently fails under the
// harness's graph capture (output stayed zeroed) -> two-kernel structure is
// the correct form; grid-wide sync is not available here.
// ---------------------------------------------------------------------------
__global__ __launch_bounds__(256) void k01_prep(
    const float* __restrict__ psi, const float* __restrict__ dw,
    const float* __restrict__ db,
    const float* __restrict__ fw1, const float* __restrict__ fw2,
    const float* __restrict__ fw3, const float* __restrict__ hw1,
    const float* __restrict__ hb1,
    short* __restrict__ wcb, short* __restrict__ fw1s,
    short* __restrict__ fw2s, short* __restrict__ fw3s) {
  __shared__ __align__(16) char sm[24832];
  const int bid = blockIdx.x;
  const int tid = threadIdx.x;

  if (bid < 1024) {           // ---- fused conv+MLP1 fragments per (h, n, G)
    float* psL    = (float*)sm;               // [25][52] f32 =  5200 B
    float* tileL  = (float*)(sm + 5200);      // [64][52] f32 = 13312 B
    float* hw1h   = (float*)(sm + 18512);     // [64][17] f32 =  4352 B
    short* tile2  = (short*)(sm + 22864);     // [16][52] bf16 = 1664 B
    float* bias16 = (float*)(sm + 24528);     // [16] f32     =    64 B
    const int h = bid >> 3;
    const int n = (bid >> 1) & 3;
    const int G = bid & 1;
    const int lane = tid & 63;
    const int w = __builtin_amdgcn_readfirstlane(tid >> 6);

    // stage psi rows for this h (25 x 49 floats, coalesced segments)
    for (int e = tid; e < 1600; e += 256) {
      const int kk = e >> 6, p = e & 63;
      if (p < 49) psL[kk * 52 + p] = psi[kk * 6272 + h * 49 + p];
    }
    // stage this (n, G) hw1 half: [64 f][16 o]
    for (int e = tid; e < 1024; e += 256) {
      const int f = e >> 4, o = e & 15;
      hw1h[f * 17 + o] = hw1[n * 2048 + f * 32 + G * 16 + o];
    }

    float dwreg[25];
#pragma unroll
    for (int kk = 0; kk < 25; ++kk) dwreg[kk] = dw[lane * 25 + kk];
    __syncthreads();

    // tileL[f][p] = sum_k dw[f,k]*psL[k][p]  (lane=f; psL reads broadcast)
    const int p0 = w * 13;
    const int pend = (p0 + 13 < 49) ? (p0 + 13) : 49;
#pragma unroll 1
    for (int p = p0; p < pend; ++p) {
      float ae = 0.f, ao = 0.f;           // 2 chains
#pragma unroll
      for (int kk = 0; kk < 24; kk += 2) {
        ae += dwreg[kk]     * psL[kk * 52 + p];
        ao += dwreg[kk + 1] * psL[(kk + 1) * 52 + p];
      }
      ae += dwreg[24] * psL[24 * 52 + p];
      tileL[lane * 52 + p] = ae + ao;
    }
    __syncthreads();

    // bias16[o] = hb1[n][G*16+o] + sum_s hw1h[s][o]*db[s]   (exact f32)
    if (tid >= 240) {
      const int o = tid - 240;
      float acc = hb1[n * 32 + G * 16 + o];
#pragma unroll 4
      for (int s = 0; s < 64; ++s) acc += hw1h[s * 17 + o] * db[s];
      bias16[o] = acc;
    }

    // tile2[o][p2,p2+1] = sum_f hw1h[f][o] * tileL[f][p2,p2+1]
    const int o = tid & 15;
#pragma unroll 1
    for (int pp = tid >> 4; pp < 25; pp += 16) {
      const int p2 = pp * 2;
      float a0 = 0.f, a1 = 0.f, a2 = 0.f, a3 = 0.f;   // 4 chains
#pragma unroll 4
      for (int f = 0; f < 64; f += 2) {
        const float wv0 = hw1h[f * 17 + o];
        const float wv1 = hw1h[(f + 1) * 17 + o];
        a0 += wv0 * tileL[f * 52 + p2];
        a1 += wv0 * tileL[f * 52 + p2 + 1];
        a2 += wv1 * tileL[(f + 1) * 52 + p2];
        a3 += wv1 * tileL[(f + 1) * 52 + p2 + 1];
      }
      tile2[o * 52 + p2] = f2bf(a0 + a2);
      if (p2 + 1 < 49) tile2[o * 52 + p2 + 1] = f2bf(a1 + a3);
    }
    __syncthreads();

    // emission: this half's 2048 shorts (nt bit == G)
    short* outp = wcb + h * 16384 + n * 4096;
    for (int q = tid; q < 2048; q += 256) {
      const int sub = q & 511;
      const int pk = q >> 9;            // par*2 + kt
      const int par = pk >> 1, kt = pk & 1;
      const int jj = sub & 7, ln = (sub >> 3) & 63;
      const int k = kt * 32 + ((ln >> 4) << 3) + jj;
      const int ol = ln & 15;
      const int r = k >> 3, dlt = k & 7;
      const int j = par ? (dlt - 1) : dlt;
      short v = 0;
      if (r < 7 && j >= 0 && j < 7) v = tile2[ol * 52 + r * 7 + j];
      if (k == 56) v = f2bf(bias16[ol]);   // bias in dead K-slot
      outp[par * 2048 + kt * 1024 + G * 512 + sub] = v;
    }
    return;
  }

  if (bid < 1040) {           // ---- fw2 kt-tile transpose: K rows 32, N 256
    short* S = (short*)sm;               // [32][260]
    const int kt = bid - 1024;
    const float* src = fw2 + kt * 8192;
    for (int q = tid; q < 2048; q += 256) {
      const int lin = q * 4;
      const int kk = lin >> 8, nn = lin & 255;
      st4bf(S + kk * 260 + nn, *(const float4*)(src + lin));
    }
    __syncthreads();
    short* dst = fw2s + kt * 8192;
    for (int q = tid; q < 8192; q += 256) {
      const int jj = q & 7, lane = (q >> 3) & 63, nt = q >> 9;
      const int kk = (lane >> 4) * 8 + jj, nn = nt * 16 + (lane & 15);
      dst[q] = S[kk * 260 + nn];
    }
    return;
  }

  if (bid < 1042) {           // ---- fw1 transpose half X: K 32, N 256
    const int X = bid - 1040;
    short* S = (short*)sm;               // [32][260]
    for (int q = tid; q < 2048; q += 256) {
      const int lin = q * 4;
      const int kk = lin >> 8, nn = lin & 255;
      st4bf(S + kk * 260 + nn, *(const float4*)(fw1 + kk * 512 + X * 256 + nn));
    }
    __syncthreads();
    for (int q = tid; q < 8192; q += 256) {
      const int jj = q & 7, lane = (q >> 3) & 63, ntl = q >> 9;
      const int kk = (lane >> 4) * 8 + jj, nn = ntl * 16 + (lane & 15);
      fw1s[X * 8192 + q] = S[kk * 260 + nn];
    }
    return;
  }

  {                           // ---- bid 1042: fw3 transpose: K 256, N 32
    short* S = (short*)sm;               // [256][36]
    for (int q = tid; q < 2048; q += 256) {
      const int lin = q * 4;
      const int kk = lin >> 5, nn = lin & 31;
      st4bf(S + kk * 36 + nn, *(const float4*)(fw3 + lin));
    }
    __syncthreads();
    for (int q = tid; q < 8192; q += 256) {
      const int jj = q & 7, lane = (q >> 3) & 63;
      const int nt = (q >> 9) & 1, kt = q >> 10;
      const int kk = kt * 32 + (lane >> 4) * 8 + jj, nn = nt * 16 + (lane & 15);
      fw3s[q] = S[kk * 36 + nn];
    }
  }
}

// ---------------------------------------------------------------------------
// K23: DISCO conv (hw1-folded, bias-in-MFMA) + head-MLP tail + final MLP.
// grid (8,128,2), block 256, LDS 20384 B, cap 64 -> 8 blocks/CU (R9 A/B:
// cap-8-with-spill 75.8 < cap-7-spill-free 78.5; scratch traffic is free at
// <10% HBM util, the 8th block's latency hiding wins). R10's tap-prefetch
// pipeline stays REVERTED (+16 live regs -> deeper spill, 75.8 -> 80.3).
// Guard-only zero-fill kept.
// LDS map: phase A sX [0,17920) + guard [17920,18080) + sM [18080,20384);
// phase B sT1h/sT2 [0,16896) alias sX (sM survives), sO f32 behind barrier.
// ---------------------------------------------------------------------------
__global__ __launch_bounds__(256, 8) void k23_fused(
    const float* __restrict__ x,    const short* __restrict__ wcb,
    const float* __restrict__ hw2,  const float* __restrict__ hb2,
    const short* __restrict__ fw1s, const short* __restrict__ fw2s,
    const short* __restrict__ fw3s,
    const float* __restrict__ fb1,  const float* __restrict__ fb2,
    const float* __restrict__ fb3,  float* __restrict__ outb) {
  __shared__ __align__(16) char smem[20384];
  short* sX = (short*)smem;                  // [32 ch][7 slots x 40]
  short* sM = (short*)(smem + 18080);        // [32][36] bf16

  const int tid = threadIdx.x;
  int w0, b, h, lin;
  tile_map(w0, b, h, lin);

  const int lane = tid & 63, lm = lane & 15, lq = lane >> 4;
  const int n = tid >> 6;  // wave == head in phase A
  const int idx16 = (lane ^ 16) << 2;        // bpermute byte indices
  const int idx32 = (lane ^ 32) << 2;
  const unsigned injm = (lq == 3) ? 0xFFFFu : 0u;   // 1.0-tap inject mask

  const float hb2n = hb2[n];

  // zero only the 160B guard (c=31's virtual slot-7 taps land here; must be
  // finite-zero). sX is fully overwritten by staging; sM is write-before-read.
  if (tid < 10) {
    int4 z; z.x = z.y = z.z = z.w = 0;
    ((int4*)(smem + 17920))[tid] = z;
  }

  // stage x tile as bf16; channel stride 280 shorts; row r -> slot
  // {0,2,4,6,1,3,5} (slot stride 40 shorts) for conflict-free gathers
#pragma unroll 1
  for (int r = 0; r < 7; ++r) {
    int hr = h - 3 + r; hr = hr < 0 ? 0 : (hr > 127 ? 127 : hr);
    const int slot = (r < 4) ? (2 * r) : (2 * r - 7);
    const float* __restrict__ xrow = x + (size_t)((b * 128 + hr) * 256) * 34;
    short* __restrict__ sxr = sX + slot * 40;
    for (int e = tid; e < 39 * 16; e += 256) {
      const int c2 = e & 15;
      const int wp = e >> 4;
      const int wr = (w0 - 3 + wp) & 255;
      const float2 v = *(const float2*)&xrow[wr * 34 + c2 * 2];
      short* dp = sxr + (c2 * 2) * 280 + wp;
      dp[0]   = f2bf_fast(v.x);
      dp[280] = f2bf_fast(v.y);
    }
  }
  __syncthreads();

  const int* tpB = (const int*)sX;

  // per-lane hw2 scale for this lane's 8 o-rows (par-invariant, hoisted)
  const float4 w0v = *(const float4*)(hw2 + n * 32 + lq * 4);
  const float4 w1v = *(const float4*)(hw2 + n * 32 + 16 + lq * 4);

  // ---- phase A: A=weights(rows=o, bias in k=56), B=taps -> D[o, pixel]
#pragma unroll 1
  for (int par = 0; par < 2; ++par) {
    bfrag cw[2][2];
#pragma unroll
    for (int kt = 0; kt < 2; ++kt)
#pragma unroll
      for (int nt = 0; nt < 2; ++nt)
        cw[kt][nt] = *(const bfrag*)(wcb + h * 16384 + n * 4096 +
                         ((par * 2 + kt) * 2 + nt) * 512 + lane * 8);

#pragma unroll 1
    for (int i = 0; i < 8; ++i) {
      const int c = n * 8 + i;

      // tap B-frags: lane lm = pixel; u0 rows 0-3 (slots 2lq),
      // u1 rows 4-7 (slots 2lq+1)
      const int base0 = c * 140 + lq * 40 + lm;
      bfi4 u0, u1;
      u0.i.x = tpB[base0];      u0.i.y = tpB[base0 + 1];
      u0.i.z = tpB[base0 + 2];  u0.i.w = tpB[base0 + 3];
      u1.i.x = tpB[base0 + 20]; u1.i.y = tpB[base0 + 21];
      u1.i.z = tpB[base0 + 22]; u1.i.w = tpB[base0 + 23];
      // inject 1.0 at K-slot 56 (lq==3, entry jj=0 of u1) -> bias row fires
      u1.i.x = (int)(((unsigned)u1.i.x & ~injm) | (0x3F80u & injm));

      ffrag h0 = {0.f, 0.f, 0.f, 0.f}, h1 = {0.f, 0.f, 0.f, 0.f};
      h0 = __builtin_amdgcn_mfma_f32_16x16x32_bf16(cw[0][0], u0.b, h0, 0, 0, 0);
      h0 = __builtin_amdgcn_mfma_f32_16x16x32_bf16(cw[1][0], u1.b, h0, 0, 0, 0);
      h1 = __builtin_amdgcn_mfma_f32_16x16x32_bf16(cw[0][1], u0.b, h1, 0, 0, 0);
      h1 = __builtin_amdgcn_mfma_f32_16x16x32_bf16(cw[1][1], u1.b, h1, 0, 0, 0);

      // in-lane o-contraction (bias already in h), then 4-way lq reduce
      float s0 = gelu_f(h0[0]) * w0v.x;
      s0 += gelu_f(h0[1]) * w0v.y;
      s0 += gelu_f(h0[2]) * w0v.z;
      s0 += gelu_f(h0[3]) * w0v.w;
      float s1 = gelu_f(h1[0]) * w1v.x;
      s1 += gelu_f(h1[1]) * w1v.y;
      s1 += gelu_f(h1[2]) * w1v.z;
      s1 += gelu_f(h1[3]) * w1v.w;
      union { float f; int i; } sv, t1, t2;
      sv.f = s0 + s1;
      t1.i = __builtin_amdgcn_ds_bpermute(idx16, sv.i);
      sv.f += t1.f;
      t2.i = __builtin_amdgcn_ds_bpermute(idx32, sv.i);
      const float tot = sv.f + t2.f;

      const int p = 2 * lm + par;
      const float res = bf2f(sX[c * 280 + 243 + p]);  // center tap (slot 6)
      if (lq == 0) sM[p * 36 + c] = f2bf_fast(tot + hb2n + res);
    }
  }
  __syncthreads();

  // ---- phase B: fused MLP 32->512(gelu)->256(gelu)->32 (+residual)
  short* sT1h = (short*)smem;
  short* sT2  = (short*)smem;
  float* sO   = (float*)smem;
  const int wave = n;
  const int koff = lq * 8;
  const int mt3 = wave & 1;
  const int nt3 = wave >> 1;
  const int col3 = nt3 * 16 + lm;
  const int pixg = (b * 128 + h) * 256 + w0;
  const int n0 = wave * 4;

  ffrag acc[2][4];
#pragma unroll
  for (int mt = 0; mt < 2; ++mt)
#pragma unroll
    for (int ni = 0; ni < 4; ++ni) acc[mt][ni] = ffrag{0.f, 0.f, 0.f, 0.f};
  const short* w2base = fw2s + n0 * 512 + lane * 8;

#pragma unroll 1
  for (int H = 0; H < 2; ++H) {
    // layer 1, half H: A=fw1 frag (rows=ff1 cols), B=sM (cols=pixels)
#pragma unroll
    for (int ni = 0; ni < 4; ++ni) {
      const bfrag b1f = *(const bfrag*)(fw1s +
                          (H * 16 + wave * 4 + ni) * 512 + lane * 8);
      const int ntl = wave * 4 + ni;
      const float4 fb1v = *(const float4*)(fb1 + H * 256 + ntl * 16 + lq * 4);
#pragma unroll
      for (int mt = 0; mt < 2; ++mt) {
        const bfrag aFm = *(const bfrag*)(sM + (mt * 16 + lm) * 36 + koff);
        ffrag cc = {0.f, 0.f, 0.f, 0.f};
        cc = __builtin_amdgcn_mfma_f32_16x16x32_bf16(b1f, aFm, cc, 0, 0, 0);
        // D rows = 4 consecutive ff1 cols, col = pixel mt*16+lm -> b64 store
        int2 wv;
        wv.x = pkbf(gelu_f(cc[0] + fb1v.x), gelu_f(cc[1] + fb1v.y));
        wv.y = pkbf(gelu_f(cc[2] + fb1v.z), gelu_f(cc[3] + fb1v.w));
        *(int2*)(sT1h + (mt * 16 + lm) * 264 + ntl * 16 + lq * 4) = wv;
      }
    }
    __syncthreads();

    // layer 2: A=fw2 frag (rows=ff2 cols), B=sT1h (cols=pixels)
#pragma unroll 1
    for (int kt = 0; kt < 8; ++kt) {
      const bfrag a0 = *(const bfrag*)(sT1h + lm * 264 + kt * 32 + koff);
      const bfrag a1 = *(const bfrag*)(sT1h + (16 + lm) * 264 + kt * 32 + koff);
#pragma unroll
      for (int np = 0; np < 2; ++np) {
        const bfrag bv0 = *(const bfrag*)(w2base + (H * 8 + kt) * 8192 + (2 * np) * 512);
        const bfrag bv1 = *(const bfrag*)(w2base + (H * 8 + kt) * 8192 + (2 * np + 1) * 512);
        acc[0][2 * np]     = __builtin_amdgcn_mfma_f32_16x16x32_bf16(bv0, a0, acc[0][2 * np], 0, 0, 0);
        acc[1][2 * np]     = __builtin_amdgcn_mfma_f32_16x16x32_bf16(bv0, a1, acc[1][2 * np], 0, 0, 0);
        acc[0][2 * np + 1] = __builtin_amdgcn_mfma_f32_16x16x32_bf16(bv1, a0, acc[0][2 * np + 1], 0, 0, 0);
        acc[1][2 * np + 1] = __builtin_amdgcn_mfma_f32_16x16x32_bf16(bv1, a1, acc[1][2 * np + 1], 0, 0, 0);
      }
    }
    __syncthreads();   // before next half overwrites sT1h
  }

  // t2 epilogue: acc rows = 4 consecutive ff2 cols, col = pixel -> b64 store
#pragma unroll
  for (int mt = 0; mt < 2; ++mt)
#pragma unroll
    for (int ni = 0; ni < 4; ++ni) {
      const float4 fb2v = *(const float4*)(fb2 + (n0 + ni) * 16 + lq * 4);
      int2 wv;
      wv.x = pkbf(gelu_f(acc[mt][ni][0] + fb2v.x), gelu_f(acc[mt][ni][1] + fb2v.y));
      wv.y = pkbf(gelu_f(acc[mt][ni][2] + fb2v.z), gelu_f(acc[mt][ni][3] + fb2v.w));
      *(int2*)(sT2 + (mt * 16 + lm) * 264 + (n0 + ni) * 16 + lq * 4) = wv;
    }
  __syncthreads();

  // layer 3 (reads sT2; D rows = pixels as before)
  ffrag c3 = {0.f, 0.f, 0.f, 0.f};
  const short* sA3 = sT2 + (mt3 * 16 + lm) * 264 + koff;
#pragma unroll
  for (int kt = 0; kt < 8; ++kt) {
    const bfrag a = *(const bfrag*)(sA3 + kt * 32);
    const bfrag bw = *(const bfrag*)(fw3s + nt3 * 512 + kt * 1024 + lane * 8);
    c3 = __builtin_amdgcn_mfma_f32_16x16x32_bf16(a, bw, c3, 0, 0, 0);
  }
  __syncthreads();   // all sT2 reads done before sO overwrite
  {
    const float bias = fb3[col3];
#pragma unroll
    for (int r = 0; r < 4; ++r) {
      const int row = mt3 * 16 + lq * 4 + r;
      const float res = bf2f(sM[row * 36 + col3]);
      sO[row * 34 + col3] = c3[r] + bias + res;
    }
  }
  if (tid < 32) {   // sincos passthrough (x row L2-hot)
    const float2 scv =
        *(const float2*)&x[(size_t)(((b * 128 + h) * 256 + w0 + tid)) * 34 + 32];
    sO[tid * 34 + 32] = scv.x;
    sO[tid * 34 + 33] = scv.y;
  }
  __syncthreads();
  {
    const float4* sp = (const float4*)sO;           // 1088 floats = 272 f4
    float4* dp = (float4*)(outb + (size_t)pixg * 34);
    for (int e = tid; e < 272; e += 256) dp[e] = sp[e];
  }
}

// ---------------------------------------------------------------------------
extern "C" void kernel_launch(void* const* d_in, const int* in_sizes, int n_in,
                              void* d_out, int out_size, void* d_ws, size_t ws_size,
                              hipStream_t stream) {
  const float* x   = (const float*)d_in[0];
  const float* psi = (const float*)d_in[1];
  const float* dw  = (const float*)d_in[2];
  const float* db  = (const float*)d_in[3];
  const float* hw1 = (const float*)d_in[4];
  const float* hb1 = (const float*)d_in[5];
  const float* hw2 = (const float*)d_in[6];
  const float* hb2 = (const float*)d_in[7];
  const float* fw1 = (const float*)d_in[8];
  const float* fb1 = (const float*)d_in[9];
  const float* fw2 = (const float*)d_in[10];
  const float* fb2 = (const float*)d_in[11];
  const float* fw3 = (const float*)d_in[12];
  const float* fb3 = (const float*)d_in[13];
  float* outb = (float*)d_out;

  // workspace (~4.5 MB)
  short* wcb  = (short*)d_ws;        // 128*16384 = 2097152 shorts
  short* fw1s = wcb + 2097152;       // 16384
  short* fw2s = fw1s + 16384;        // 131072
  short* fw3s = fw2s + 131072;       // 8192

  hipLaunchKernelGGL(k01_prep, dim3(1043), dim3(256), 0, stream,
                     psi, dw, db, fw1, fw2, fw3, hw1, hb1,
                     wcb, fw1s, fw2s, fw3s);
  hipLaunchKernelGGL(k23_fused, dim3(8, 128, 2), dim3(256), 0, stream,
                     x, wcb, hw2, hb2,
                     fw1s, fw2s, fw3s, fb1, fb2, fb3, outb);
}